// Round 8
// baseline (613.980 us; speedup 1.0000x reference)
//
#include <hip/hip_runtime.h>

typedef _Float16 half8 __attribute__((ext_vector_type(8)));
typedef float floatx4 __attribute__((ext_vector_type(4)));
typedef int intx4 __attribute__((ext_vector_type(4)));

#define CIN 32
#define COUT 32
#define KOFF 27
#define EPSV 1e-5f
#define CVT_BLOCKS 2048
#define BN_BLOCKS 2048

// ---------------------------------------------------------------------------
// ws layout:
//   [0, (N+1)*32*2)        feats16 (f16 copy of feats + zero row at index N)
//   [+, +55296)            Wpack: B-fragments, f16
//   [align 512, +768)      stats: sum[32], sumsq[32], flag
//   [align 256, +N*32*2)   y16: pre-BN conv output in f16
// conv is at the random-64B-gather memory roofline (~3.5 TB/s L2-miss level,
// measured invariant across 4 gather structures). Round 8: prep/bn were
// DISPATCH-RATE-bound (~10 ns/workgroup x ~15.7k tiny blocks each ~= 300 us)
// -> capped 2048-block grids with grid-stride loops (guide G11).
// ---------------------------------------------------------------------------

// blocks [0,KOFF): pack W fragments (128 threads used).
// block KOFF: detect mask dtype, zero stats+flag.
// blocks (KOFF, KOFF+1+CVT_BLOCKS): feats fp32->f16 grid-stride (+ zero row).
__global__ void fused_prep(const float* __restrict__ feats,
                           _Float16* __restrict__ f16, int total8,
                           const float* __restrict__ W,
                           _Float16* __restrict__ wp,
                           const unsigned char* __restrict__ m,
                           int* __restrict__ flag,
                           float* __restrict__ stats) {
  int bx = blockIdx.x;
  int tid = threadIdx.x;
  if (bx < KOFF) {
    if (tid < 128) {
      int ko = bx;
      int h = tid >> 6;        // 2 halves
      int lane = tid & 63;
      int col = lane & 15, quad = lane >> 4;
      half8 p;
#pragma unroll
      for (int j = 0; j < 8; ++j) {
        int k = quad * 8 + j;
        p[j] = (_Float16)W[(ko * CIN + k) * COUT + h * 16 + col];
      }
      *(half8*)(wp + ((size_t)(ko * 2 + h) * 64 + lane) * 8) = p;
    }
    return;
  }
  if (bx == KOFF) {
    // int32 mask => bytes at offset%4!=0 all zero; byte mask => ~50% nonzero
    __shared__ int red;
    if (tid == 0) red = 0;
    __syncthreads();
    int any = 0;
    for (int i = tid; i < 4096; i += 256) {
      if ((i & 3) != 0 && m[i] != 0) any = 1;
    }
    if (any) atomicOr(&red, 1);
    __syncthreads();
    if (tid == 0) *flag = red;
    if (tid < 64) stats[tid] = 0.f;
    return;
  }
  const floatx4* in4 = (const floatx4*)feats;
  int stride = CVT_BLOCKS * 256;
  for (int t = (bx - KOFF - 1) * 256 + tid; t < total8 + 4; t += stride) {
    if (t < total8) {
      floatx4 a = __builtin_nontemporal_load(&in4[(size_t)t * 2]);
      floatx4 b = __builtin_nontemporal_load(&in4[(size_t)t * 2 + 1]);
      half8 h;
      h[0] = (_Float16)a[0]; h[1] = (_Float16)a[1];
      h[2] = (_Float16)a[2]; h[3] = (_Float16)a[3];
      h[4] = (_Float16)b[0]; h[5] = (_Float16)b[1];
      h[6] = (_Float16)b[2]; h[7] = (_Float16)b[3];
      *(half8*)(f16 + (size_t)t * 8) = h;  // temporal: keep L3-resident
    } else {
      half8 z;
#pragma unroll
      for (int j = 0; j < 8; ++j) z[j] = (_Float16)0.f;
      *(half8*)(f16 + (size_t)t * 8) = z;  // zero row at voxel index N
    }
  }
}

__launch_bounds__(256, 4)
__global__ void conv_mfma_l(const _Float16* __restrict__ f16,
                            const _Float16* __restrict__ wp,
                            const int* __restrict__ nidx,
                            const unsigned char* __restrict__ nmask,
                            const int* __restrict__ flagp,
                            _Float16* __restrict__ y16,
                            float* __restrict__ stats, int N) {
  __shared__ int lidx[4 * 64 * KOFF];   // per-wave [64][27] idx|maskbit
  __shared__ float smS[4 * 32];
  __shared__ float smQ[4 * 32];
  int wave = threadIdx.x >> 6;
  int lane = threadIdx.x & 63;
  int base = (blockIdx.x * 4 + wave) * 64;
  bool active = base < N;
  int col = lane & 15, quad = lane >> 4;
  const half8* wfrag = (const half8*)wp;
  const _Float16* fq = f16 + quad * 8;  // per-quad 16B slice of a 64B row
  int* lw = lidx + wave * (64 * KOFF);

  floatx4 acc[4][2];
#pragma unroll
  for (int t = 0; t < 4; ++t)
#pragma unroll
    for (int h = 0; h < 2; ++h) {
      acc[t][h][0] = 0.f; acc[t][h][1] = 0.f;
      acc[t][h][2] = 0.f; acc[t][h][3] = 0.f;
    }

  if (active) {
    bool bytemode = (*flagp != 0);
    int nv = N - base; if (nv > 64) nv = 64;
    if (nv == 64) {
      // coalesced fill: 1728 ints = 432 int4 (nontemporal: single-use streams)
      const intx4* gi = (const intx4*)(nidx + (size_t)base * KOFF);
      const intx4* gm4 = (const intx4*)((const int*)nmask + (size_t)base * KOFF);
      const unsigned int* gmb = (const unsigned int*)(nmask + (size_t)base * KOFF);
#pragma unroll
      for (int s = 0; s < 7; ++s) {
        int id4 = s * 64 + lane;
        if (id4 < 432) {
          intx4 iv = __builtin_nontemporal_load(&gi[id4]);
          unsigned int m0, m1, m2, m3;
          if (bytemode) {
            unsigned int mw = __builtin_nontemporal_load(&gmb[id4]);
            m0 = mw & 0xffu; m1 = mw & 0xff00u;
            m2 = mw & 0xff0000u; m3 = mw & 0xff000000u;
          } else {
            intx4 mv = __builtin_nontemporal_load(&gm4[id4]);
            m0 = (unsigned int)mv.x; m1 = (unsigned int)mv.y;
            m2 = (unsigned int)mv.z; m3 = (unsigned int)mv.w;
          }
          intx4 ov;
          ov.x = (iv.x & 0x7FFFFFFF) | (m0 ? (int)0x80000000 : 0);
          ov.y = (iv.y & 0x7FFFFFFF) | (m1 ? (int)0x80000000 : 0);
          ov.z = (iv.z & 0x7FFFFFFF) | (m2 ? (int)0x80000000 : 0);
          ov.w = (iv.w & 0x7FFFFFFF) | (m3 ? (int)0x80000000 : 0);
          *(intx4*)(lw + id4 * 4) = ov;
        }
      }
    } else {
      // guarded tail fill
      int total = nv * KOFF;
      for (int p = lane; p < total; p += 64) {
        size_t g = (size_t)base * KOFF + p;
        int iv = nidx[g];
        int mk = bytemode ? (int)nmask[g] : ((const int*)nmask)[g];
        lw[p] = (iv & 0x7FFFFFFF) | (mk ? (int)0x80000000 : 0);
      }
      for (int p = nv * KOFF + lane; p < 64 * KOFF; p += 64) lw[p] = 0;
    }
    // no barrier: each wave reads only its own LDS region

    // prologue: idx(0) -> aC gathers; idx(1) -> ivB
    half8 aC[4];
    int ivB[4];
#pragma unroll
    for (int t = 0; t < 4; ++t) {
      int v0 = lw[(t * 16 + col) * KOFF + 0];
      int sel = (v0 < 0) ? (v0 & 0x7FFFFFFF) : N;
      aC[t] = *(const half8*)(fq + ((size_t)sel << 5));
      ivB[t] = lw[(t * 16 + col) * KOFF + 1];
    }
    half8 bC0 = wfrag[lane];
    half8 bC1 = wfrag[64 + lane];

#pragma unroll
    for (int ko = 0; ko < KOFF; ++ko) {
      half8 aN[4];
      half8 bN0, bN1;
      int ivN[4];
      if (ko + 1 < KOFF) {
        bN0 = wfrag[(size_t)((ko + 1) * 2 + 0) * 64 + lane];
        bN1 = wfrag[(size_t)((ko + 1) * 2 + 1) * 64 + lane];
#pragma unroll
        for (int t = 0; t < 4; ++t) {
          int v = ivB[t];
          int sel = (v < 0) ? (v & 0x7FFFFFFF) : N;
          aN[t] = *(const half8*)(fq + ((size_t)sel << 5));
        }
      }
      if (ko + 2 < KOFF) {
#pragma unroll
        for (int t = 0; t < 4; ++t)
          ivN[t] = lw[(t * 16 + col) * KOFF + ko + 2];
      }
#pragma unroll
      for (int t = 0; t < 4; ++t) {
        acc[t][0] = __builtin_amdgcn_mfma_f32_16x16x32_f16(aC[t], bC0, acc[t][0], 0, 0, 0);
        acc[t][1] = __builtin_amdgcn_mfma_f32_16x16x32_f16(aC[t], bC1, acc[t][1], 0, 0, 0);
      }
      if (ko + 1 < KOFF) {
#pragma unroll
        for (int t = 0; t < 4; ++t) aC[t] = aN[t];
        bC0 = bN0; bC1 = bN1;
      }
      if (ko + 2 < KOFF) {
#pragma unroll
        for (int t = 0; t < 4; ++t) ivB[t] = ivN[t];
      }
    }
  }

  // ---- epilogue: y16 store + fused BN partial sums ----
  float s0 = 0.f, s1 = 0.f, q0 = 0.f, q1 = 0.f;
  if (active) {
#pragma unroll
    for (int t = 0; t < 4; ++t) {
#pragma unroll
      for (int h = 0; h < 2; ++h) {
        floatx4 c = acc[t][h];
        int co = h * 16 + col;
#pragma unroll
        for (int r = 0; r < 4; ++r) {
          int vox = base + t * 16 + quad * 4 + r;
          if (vox < N) {  // no-op when 64|N
            y16[(size_t)vox * COUT + co] = (_Float16)c[r];
            float v = c[r];
            if (h == 0) { s0 += v; q0 += v * v; }
            else        { s1 += v; q1 += v * v; }
          }
        }
      }
    }
  }
  // reduce across the 4 quads (lanes col, col+16, col+32, col+48)
  s0 += __shfl_xor(s0, 16); s0 += __shfl_xor(s0, 32);
  s1 += __shfl_xor(s1, 16); s1 += __shfl_xor(s1, 32);
  q0 += __shfl_xor(q0, 16); q0 += __shfl_xor(q0, 32);
  q1 += __shfl_xor(q1, 16); q1 += __shfl_xor(q1, 32);
  if (quad == 0) {
    smS[wave * 32 + col] = s0;
    smS[wave * 32 + 16 + col] = s1;
    smQ[wave * 32 + col] = q0;
    smQ[wave * 32 + 16 + col] = q1;
  }
  __syncthreads();
  int tid = threadIdx.x;
  if (tid < 64) {
    int co = tid & 31;
    const float* arr = (tid < 32) ? smS : smQ;
    float s = arr[co] + arr[32 + co] + arr[64 + co] + arr[96 + co];
    atomicAdd(&stats[(tid < 32 ? 0 : 32) + co], s);
  }
}

// BN finalize (per-block, from raw sums) + normalize + ReLU: y16 -> out f32.
// Grid-stride over total8 half8-groups (BN_BLOCKS blocks).
__global__ void bn_apply(const _Float16* __restrict__ y16,
                         float* __restrict__ out,
                         const float* __restrict__ stats,
                         const float* __restrict__ gamma,
                         const float* __restrict__ beta, int total8,
                         float invN) {
  __shared__ float sc_sh[64];
  int tid = threadIdx.x;
  if (tid < 32) {
    float mean = stats[tid] * invN;
    float ex2 = stats[32 + tid] * invN;
    float var = ex2 - mean * mean;
    float inv = rsqrtf(var + EPSV);
    float sc = gamma[tid] * inv;
    sc_sh[tid] = sc;
    sc_sh[32 + tid] = beta[tid] - mean * sc;
  }
  __syncthreads();
  int stride = BN_BLOCKS * 256;
  for (int t = blockIdx.x * 256 + tid; t < total8; t += stride) {
    size_t g = (size_t)t * 8;
    int co = (int)(g & 31);
    half8 v = __builtin_nontemporal_load((const half8*)(y16 + g));
    floatx4 sc0 = *(const floatx4*)&sc_sh[co];
    floatx4 sh0 = *(const floatx4*)&sc_sh[32 + co];
    floatx4 sc1 = *(const floatx4*)&sc_sh[co + 4];
    floatx4 sh1 = *(const floatx4*)&sc_sh[32 + co + 4];
    floatx4 o0, o1;
#pragma unroll
    for (int j = 0; j < 4; ++j)
      o0[j] = fmaxf(0.f, (float)v[j] * sc0[j] + sh0[j]);
#pragma unroll
    for (int j = 0; j < 4; ++j)
      o1[j] = fmaxf(0.f, (float)v[4 + j] * sc1[j] + sh1[j]);
    __builtin_nontemporal_store(o0, (floatx4*)(out + g));
    __builtin_nontemporal_store(o1, (floatx4*)(out + g + 4));
  }
}

extern "C" void kernel_launch(void* const* d_in, const int* in_sizes, int n_in,
                              void* d_out, int out_size, void* d_ws,
                              size_t ws_size, hipStream_t stream) {
  const float* feats = (const float*)d_in[0];
  const float* W = (const float*)d_in[1];
  const float* gamma = (const float*)d_in[2];
  const float* beta = (const float*)d_in[3];
  const int* nidx = (const int*)d_in[4];
  const unsigned char* nmask = (const unsigned char*)d_in[5];
  float* out = (float*)d_out;

  int N = in_sizes[0] / CIN;  // 1,000,000

  char* ws = (char*)d_ws;
  size_t f16_bytes = (size_t)(N + 1) * CIN * sizeof(_Float16);  // +1 zero row
  _Float16* f16 = (_Float16*)ws;
  _Float16* wp = (_Float16*)(ws + f16_bytes);
  size_t wp_bytes = (size_t)KOFF * 2 * 64 * 8 * sizeof(_Float16);
  size_t stats_off = ((f16_bytes + wp_bytes + 511) / 512) * 512;
  float* stats = (float*)(ws + stats_off);
  int* flag = (int*)(stats + 64);
  size_t y16_off = ((stats_off + 768 + 255) / 256) * 256;
  _Float16* y16 = (_Float16*)(ws + y16_off);

  int total8 = N * CIN / 8;
  fused_prep<<<KOFF + 1 + CVT_BLOCKS, 256, 0, stream>>>(feats, f16, total8, W,
                                                        wp, nmask, flag,
                                                        stats);

  int nwaves = (N + 63) / 64;
  int nblocks = (nwaves + 3) / 4;
  conv_mfma_l<<<nblocks, 256, 0, stream>>>(f16, wp, nidx, nmask, flag, y16,
                                           stats, N);

  int total8v = N * COUT / 8;
  bn_apply<<<BN_BLOCKS, 256, 0, stream>>>(y16, out, stats, gamma, beta,
                                          total8v, 1.0f / (float)N);
}